// Round 1
// baseline (512.359 us; speedup 1.0000x reference)
//
#include <hip/hip_runtime.h>

typedef float floatx4 __attribute__((ext_vector_type(4)));

#define BB 32
#define HH 56
#define WW 56
#define CC 256
#define PSTRIP 4
#define WSTRIPS 14                      // 56/4
#define HTILE 4                         // rows per block (4 waves, 1 row each)
#define HTILES 14                       // 56/4
#define BLOCKS_PER_IMG (HTILES * WSTRIPS)  // 196

// R7: weights move from registers to LDS.
// R6 held gk[8]+gsw[8] = 64 VGPRs of loop-invariant weights per thread,
// which (a) pinned VGPR_Count at 72 -> 4 waves/SIMD occupancy bucket and
// (b) left no registers for the 10 per-pixel tap loads to stay in flight,
// so the compiler serialized load->wait->FMA chains (all pipes <30% busy,
// latency-bound at 107us vs ~25us HBM roofline).
// Now: 16 weight rows (8 gk + 8 gsw, 16KB) staged cooperatively in LDS
// once per block (weights depend only on lane, shared by all 4 waves),
// streamed via ds_read_b128 in the inner loop (~16 reads/pixel, separate
// pipe from VMEM, contiguous 16B/lane = free 2-way bank pattern).
// Frees ~64 VGPRs -> launch_bounds(256,8) forces <=64 VGPR -> 8 waves/SIMD
// (2x occupancy) AND all 10 tap/center loads per pixel stay in flight.
// 8 blocks/CU x 16KB = 128KB LDS <= 160KB, so LDS doesn't cap occupancy.
// Everything else (XCD pinning, NT stores, wave=pixel, lane=channel-quad,
// wave-uniform tap predication) unchanged from R6.
__global__ __launch_bounds__(256, 8) void dn_kernel(
    const float* __restrict__ x,
    const float* __restrict__ gk_g,
    const float* __restrict__ gs_g,
    const float* __restrict__ beta,
    const float* __restrict__ beta_o,
    const float* __restrict__ gamma_o,
    const int* __restrict__ sdist,
    float* __restrict__ out)
{
    __shared__ float lw[16 * CC];       // rows 0-7: gk[i], rows 8-15: gsw[tt]

    const int tid = threadIdx.x;

    // Cooperative stage: 16 rows x 256 floats; 4 iters/thread, dwordx4 each.
    for (int idx = tid; idx < 16 * 64; idx += 256) {
        const int r  = idx >> 6;
        const int cq = (idx & 63) << 2;
        const float* src;
        if (r < 8) {
            src = gk_g + r * CC + cq;
        } else {
            const int t   = r - 8;
            const int pos = t + (t >= 4 ? 1 : 0);   // skip center of 3x3
            src = gs_g + pos * CC + cq;
        }
        *reinterpret_cast<floatx4*>(&lw[r * CC + cq]) =
            *reinterpret_cast<const floatx4*>(src);
    }

    const int d    = sdist[0];                 // surround_dist (=1)
    const int xcd  = blockIdx.x & 7;
    const int q    = blockIdx.x >> 3;          // 0..783
    const int b    = xcd + ((q / BLOCKS_PER_IMG) << 3);
    const int t0   = q % BLOCKS_PER_IMG;
    const int h    = (t0 / WSTRIPS) * HTILE + (tid >> 6);
    const int w0   = (t0 % WSTRIPS) * PSTRIP;
    const int lane = tid & 63;
    const int c0   = lane << 2;                // own channel quad
    const int cg   = c0 & ~7;                  // group base (8 ch)

    const int tap_kh[8] = {0,0,0,1,1,2,2,2};
    const int tap_kw[8] = {0,1,2,0,2,0,1,2};

    // Per-thread constants stay in registers (12 VGPRs).
    floatx4 betav = *reinterpret_cast<const floatx4*>(beta + c0);
    betav += 1e-6f;                            // BETA_MIN
    const floatx4 gov = *reinterpret_cast<const floatx4*>(gamma_o + c0);
    const floatx4 bov = *reinterpret_cast<const floatx4*>(beta_o  + c0);

    const float* xb   = x + (size_t)b * HH * WW * CC;
    const float* xrow = xb + (size_t)h * WW * CC;
    float*       orow = out + ((size_t)(b * HH + h) * WW) * CC;
    const float* wk   = lw + c0;               // per-lane LDS weight base

    __syncthreads();

#pragma unroll
    for (int j = 0; j < PSTRIP; ++j) {
        const int w = w0 + j;
        const float* cp = xrow + w * CC;

        // center: full 8-ch group (lane pairs duplicate-read the same 32B)
        floatx4 cxa = *reinterpret_cast<const floatx4*>(cp + cg);
        floatx4 cxb = *reinterpret_cast<const floatx4*>(cp + cg + 4);

        // 8 neighbor taps, own quad only; wave-uniform predication
        floatx4 tp[8];
#pragma unroll
        for (int tt = 0; tt < 8; ++tt) {
            const int hh = h + (tap_kh[tt] - 1) * d;
            const int w2 = w + (tap_kw[tt] - 1) * d;
            floatx4 v = {0.f, 0.f, 0.f, 0.f};
            if ((unsigned)hh < HH && (unsigned)w2 < WW)
                v = *reinterpret_cast<const floatx4*>(
                        xb + (size_t)(hh * WW + w2) * CC + c0);
            tp[tt] = v;
        }

        // select own raw quad early so cxa/cxb die into the squares
        const floatx4 cxo = (lane & 1) ? cxb : cxa;
        const floatx4 sqa = cxa * cxa, sqb = cxb * cxb;

        // Pk: 8 group inputs x own 4 outputs, weights streamed from LDS
        floatx4 acc = betav;
#pragma unroll
        for (int i = 0; i < 4; ++i)
            acc += sqa[i] * *reinterpret_cast<const floatx4*>(wk + i * CC);
#pragma unroll
        for (int i = 0; i < 4; ++i)
            acc += sqb[i] * *reinterpret_cast<const floatx4*>(wk + (4 + i) * CC);
        // Ps: 8 depthwise taps on own quad, weights streamed from LDS
#pragma unroll
        for (int tt = 0; tt < 8; ++tt)
            acc += (tp[tt] * tp[tt]) *
                   *reinterpret_cast<const floatx4*>(wk + (8 + tt) * CC);

        floatx4 res;
#pragma unroll
        for (int o = 0; o < 4; ++o)
            res[o] = cxo[o] * __builtin_amdgcn_rsqf(acc[o]) * gov[o] + bov[o];

        __builtin_nontemporal_store(res,
            reinterpret_cast<floatx4*>(orow + w * CC + c0));
    }
}

extern "C" void kernel_launch(void* const* d_in, const int* in_sizes, int n_in,
                              void* d_out, int out_size, void* d_ws, size_t ws_size,
                              hipStream_t stream) {
    const float* x       = (const float*)d_in[0];
    const float* gamma_k = (const float*)d_in[1];
    const float* gamma_s = (const float*)d_in[2];
    const float* beta    = (const float*)d_in[3];
    const float* beta_o  = (const float*)d_in[4];
    const float* gamma_o = (const float*)d_in[5];
    const int*   sdist   = (const int*)d_in[6];
    float* out = (float*)d_out;

    const int blocks = BB * BLOCKS_PER_IMG;   // 6272
    dn_kernel<<<blocks, 256, 0, stream>>>(x, gamma_k, gamma_s, beta,
                                          beta_o, gamma_o, sdist, out);
}

// Round 2
// 390.414 us; speedup vs baseline: 1.3123x; 1.3123x over previous
//
#include <hip/hip_runtime.h>

typedef float floatx4 __attribute__((ext_vector_type(4)));

#define BB 32
#define HH 56
#define WW 56
#define CC 256
#define PSTRIP 4
#define WSTRIPS 14                      // 56/4
#define HTILE 4                         // rows per block (4 waves, 1 row each)
#define HTILES 14                       // 56/4
#define BLOCKS_PER_IMG (HTILES * WSTRIPS)  // 196

// R8: R7's LDS-weight structure, but launch_bounds(256,5) instead of (256,8).
// R7 post-mortem: forcing 8 waves/SIMD capped VGPRs at 64; the allocator
// spilled the 8 in-flight tap quads to scratch -> FETCH 935MB / WRITE 570MB
// (10x traffic, matches 16B*8*2 per pixel spill arithmetic) -> 389us even
// at 4 TB/s. But R7 PROVED the occupancy mechanism: 86% occupancy sustained
// 4 TB/s. The working set (tp[8]=32 + consts 12 + addr ~15 + acc/sq ~16)
// needs ~80-100 VGPRs. (256,5) -> cap 102: holds it with zero spill while
// giving 5 waves/SIMD = 62.5% occupancy (2.2x R6's 28%).
// Tripwire: FETCH must return to ~50MB, WRITE to ~100MB. If not, still
// spilling -> drop to (256,4).
// Weights (8 gk + 8 gsw rows, 16KB) stay in LDS: shared by all 4 waves,
// ds_read_b128 contiguous 16B/lane = free bank pattern, frees 64 VGPRs vs R6.
__global__ __launch_bounds__(256, 5) void dn_kernel(
    const float* __restrict__ x,
    const float* __restrict__ gk_g,
    const float* __restrict__ gs_g,
    const float* __restrict__ beta,
    const float* __restrict__ beta_o,
    const float* __restrict__ gamma_o,
    const int* __restrict__ sdist,
    float* __restrict__ out)
{
    __shared__ float lw[16 * CC];       // rows 0-7: gk[i], rows 8-15: gsw[tt]

    const int tid = threadIdx.x;

    // Cooperative stage: 16 rows x 256 floats; 4 iters/thread, dwordx4 each.
    for (int idx = tid; idx < 16 * 64; idx += 256) {
        const int r  = idx >> 6;
        const int cq = (idx & 63) << 2;
        const float* src;
        if (r < 8) {
            src = gk_g + r * CC + cq;
        } else {
            const int t   = r - 8;
            const int pos = t + (t >= 4 ? 1 : 0);   // skip center of 3x3
            src = gs_g + pos * CC + cq;
        }
        *reinterpret_cast<floatx4*>(&lw[r * CC + cq]) =
            *reinterpret_cast<const floatx4*>(src);
    }

    const int d    = sdist[0];                 // surround_dist (=1)
    const int xcd  = blockIdx.x & 7;
    const int q    = blockIdx.x >> 3;          // 0..783
    const int b    = xcd + ((q / BLOCKS_PER_IMG) << 3);
    const int t0   = q % BLOCKS_PER_IMG;
    const int h    = (t0 / WSTRIPS) * HTILE + (tid >> 6);
    const int w0   = (t0 % WSTRIPS) * PSTRIP;
    const int lane = tid & 63;
    const int c0   = lane << 2;                // own channel quad
    const int cg   = c0 & ~7;                  // group base (8 ch)

    const int tap_kh[8] = {0,0,0,1,1,2,2,2};
    const int tap_kw[8] = {0,1,2,0,2,0,1,2};

    // Per-thread constants stay in registers (12 VGPRs).
    floatx4 betav = *reinterpret_cast<const floatx4*>(beta + c0);
    betav += 1e-6f;                            // BETA_MIN
    const floatx4 gov = *reinterpret_cast<const floatx4*>(gamma_o + c0);
    const floatx4 bov = *reinterpret_cast<const floatx4*>(beta_o  + c0);

    const float* xb   = x + (size_t)b * HH * WW * CC;
    const float* xrow = xb + (size_t)h * WW * CC;
    float*       orow = out + ((size_t)(b * HH + h) * WW) * CC;
    const float* wk   = lw + c0;               // per-lane LDS weight base

    __syncthreads();

#pragma unroll
    for (int j = 0; j < PSTRIP; ++j) {
        const int w = w0 + j;
        const float* cp = xrow + w * CC;

        // center: full 8-ch group (lane pairs duplicate-read the same 32B)
        floatx4 cxa = *reinterpret_cast<const floatx4*>(cp + cg);
        floatx4 cxb = *reinterpret_cast<const floatx4*>(cp + cg + 4);

        // 8 neighbor taps, own quad only; wave-uniform predication
        floatx4 tp[8];
#pragma unroll
        for (int tt = 0; tt < 8; ++tt) {
            const int hh = h + (tap_kh[tt] - 1) * d;
            const int w2 = w + (tap_kw[tt] - 1) * d;
            floatx4 v = {0.f, 0.f, 0.f, 0.f};
            if ((unsigned)hh < HH && (unsigned)w2 < WW)
                v = *reinterpret_cast<const floatx4*>(
                        xb + (size_t)(hh * WW + w2) * CC + c0);
            tp[tt] = v;
        }

        // select own raw quad early so cxa/cxb die into the squares
        const floatx4 cxo = (lane & 1) ? cxb : cxa;
        const floatx4 sqa = cxa * cxa, sqb = cxb * cxb;

        // Pk: 8 group inputs x own 4 outputs, weights streamed from LDS
        floatx4 acc = betav;
#pragma unroll
        for (int i = 0; i < 4; ++i)
            acc += sqa[i] * *reinterpret_cast<const floatx4*>(wk + i * CC);
#pragma unroll
        for (int i = 0; i < 4; ++i)
            acc += sqb[i] * *reinterpret_cast<const floatx4*>(wk + (4 + i) * CC);
        // Ps: 8 depthwise taps on own quad, weights streamed from LDS
#pragma unroll
        for (int tt = 0; tt < 8; ++tt)
            acc += (tp[tt] * tp[tt]) *
                   *reinterpret_cast<const floatx4*>(wk + (8 + tt) * CC);

        floatx4 res;
#pragma unroll
        for (int o = 0; o < 4; ++o)
            res[o] = cxo[o] * __builtin_amdgcn_rsqf(acc[o]) * gov[o] + bov[o];

        __builtin_nontemporal_store(res,
            reinterpret_cast<floatx4*>(orow + w * CC + c0));
    }
}

extern "C" void kernel_launch(void* const* d_in, const int* in_sizes, int n_in,
                              void* d_out, int out_size, void* d_ws, size_t ws_size,
                              hipStream_t stream) {
    const float* x       = (const float*)d_in[0];
    const float* gamma_k = (const float*)d_in[1];
    const float* gamma_s = (const float*)d_in[2];
    const float* beta    = (const float*)d_in[3];
    const float* beta_o  = (const float*)d_in[4];
    const float* gamma_o = (const float*)d_in[5];
    const int*   sdist   = (const int*)d_in[6];
    float* out = (float*)d_out;

    const int blocks = BB * BLOCKS_PER_IMG;   // 6272
    dn_kernel<<<blocks, 256, 0, stream>>>(x, gamma_k, gamma_s, beta,
                                          beta_o, gamma_o, sdist, out);
}

// Round 4
// 226.781 us; speedup vs baseline: 2.2593x; 1.7215x over previous
//
#include <hip/hip_runtime.h>

typedef float floatx4 __attribute__((ext_vector_type(4)));

#define BB 32
#define HH 56
#define WW 56
#define CC 256
#define PSTRIP 4
#define WSTRIPS 14                      // 56/4
#define HTILE 4                         // rows per block (4 waves, 1 row each)
#define HTILES 14                       // 56/4
#define BLOCKS_PER_IMG (HTILES * WSTRIPS)  // 196

// R10: occupancy pinned to 5 waves/SIMD via LDS SIZE, not attributes.
// R7/R8 post-mortem: the AMDGPU allocator sets its VGPR budget from max
// ACHIEVABLE occupancy (launch_bounds' 2nd arg is only a floor). At 16KB
// LDS it targeted 8-10 blocks/CU -> 48-64 VGPR budget -> spilled the
// ~80-100-reg tap working set -> +0.7-1.4GB scratch traffic (R8: FETCH
// 528MB/WRITE 344MB vs clean 50/100MB). R9 tried amdgpu_waves_per_eu(5,5)
// but the bench infra failed; this round pins occupancy with zero exotic
// features: declare 32KB LDS -> max 160/32 = 5 blocks/CU -> compiler's
// occupancy target = 5 waves/SIMD -> VGPR budget 512/5 ~ 102 -> working
// set fits, zero spill. 5 waves/SIMD = 62.5% occupancy; per the measured
// BW-vs-occupancy curve (28%->1.4, 55%->3.4, 86%->4.0 TB/s) that sustains
// ~3.5TB/s; clean 154MB => ~45us/dispatch.
// Tripwires: VGPR_Count ~84-102 (<=64 = budget didn't relax);
// FETCH ~50MB, WRITE ~100MB (else still spilling); LDS_Block_Size 32768.
// Weights (8 gk + 8 gsw rows) live in the first 16KB of LDS: shared by
// all 4 waves, ds_read_b128 contiguous 16B/lane = 0 bank conflicts.
__global__ __launch_bounds__(256) void dn_kernel(
    const float* __restrict__ x,
    const float* __restrict__ gk_g,
    const float* __restrict__ gs_g,
    const float* __restrict__ beta,
    const float* __restrict__ beta_o,
    const float* __restrict__ gamma_o,
    const int* __restrict__ sdist,
    float* __restrict__ out)
{
    // 32KB total: first 16 rows hold weights, rest is occupancy-pinning pad.
    __shared__ float lw[32 * CC];

    const int tid = threadIdx.x;

    // Cooperative stage: 16 rows x 256 floats; 4 iters/thread, dwordx4 each.
    for (int idx = tid; idx < 16 * 64; idx += 256) {
        const int r  = idx >> 6;
        const int cq = (idx & 63) << 2;
        const float* src;
        if (r < 8) {
            src = gk_g + r * CC + cq;
        } else {
            const int t   = r - 8;
            const int pos = t + (t >= 4 ? 1 : 0);   // skip center of 3x3
            src = gs_g + pos * CC + cq;
        }
        *reinterpret_cast<floatx4*>(&lw[r * CC + cq]) =
            *reinterpret_cast<const floatx4*>(src);
    }

    const int d    = sdist[0];                 // surround_dist (=1)
    const int xcd  = blockIdx.x & 7;
    const int q    = blockIdx.x >> 3;          // 0..783
    const int b    = xcd + ((q / BLOCKS_PER_IMG) << 3);
    const int t0   = q % BLOCKS_PER_IMG;
    const int h    = (t0 / WSTRIPS) * HTILE + (tid >> 6);
    const int w0   = (t0 % WSTRIPS) * PSTRIP;
    const int lane = tid & 63;
    const int c0   = lane << 2;                // own channel quad
    const int cg   = c0 & ~7;                  // group base (8 ch)

    const int tap_kh[8] = {0,0,0,1,1,2,2,2};
    const int tap_kw[8] = {0,1,2,0,2,0,1,2};

    // Per-thread constants stay in registers (12 VGPRs).
    floatx4 betav = *reinterpret_cast<const floatx4*>(beta + c0);
    betav += 1e-6f;                            // BETA_MIN
    const floatx4 gov = *reinterpret_cast<const floatx4*>(gamma_o + c0);
    const floatx4 bov = *reinterpret_cast<const floatx4*>(beta_o  + c0);

    const float* xb   = x + (size_t)b * HH * WW * CC;
    const float* xrow = xb + (size_t)h * WW * CC;
    float*       orow = out + ((size_t)(b * HH + h) * WW) * CC;
    const float* wk   = lw + c0;               // per-lane LDS weight base

    __syncthreads();

#pragma unroll
    for (int j = 0; j < PSTRIP; ++j) {
        const int w = w0 + j;
        const float* cp = xrow + w * CC;

        // center: full 8-ch group (lane pairs duplicate-read the same 32B)
        floatx4 cxa = *reinterpret_cast<const floatx4*>(cp + cg);
        floatx4 cxb = *reinterpret_cast<const floatx4*>(cp + cg + 4);

        // 8 neighbor taps, own quad only; wave-uniform predication
        floatx4 tp[8];
#pragma unroll
        for (int tt = 0; tt < 8; ++tt) {
            const int hh = h + (tap_kh[tt] - 1) * d;
            const int w2 = w + (tap_kw[tt] - 1) * d;
            floatx4 v = {0.f, 0.f, 0.f, 0.f};
            if ((unsigned)hh < HH && (unsigned)w2 < WW)
                v = *reinterpret_cast<const floatx4*>(
                        xb + (size_t)(hh * WW + w2) * CC + c0);
            tp[tt] = v;
        }

        // select own raw quad early so cxa/cxb die into the squares
        const floatx4 cxo = (lane & 1) ? cxb : cxa;
        const floatx4 sqa = cxa * cxa, sqb = cxb * cxb;

        // Pk: 8 group inputs x own 4 outputs, weights streamed from LDS
        floatx4 acc = betav;
#pragma unroll
        for (int i = 0; i < 4; ++i)
            acc += sqa[i] * *reinterpret_cast<const floatx4*>(wk + i * CC);
#pragma unroll
        for (int i = 0; i < 4; ++i)
            acc += sqb[i] * *reinterpret_cast<const floatx4*>(wk + (4 + i) * CC);
        // Ps: 8 depthwise taps on own quad, weights streamed from LDS
#pragma unroll
        for (int tt = 0; tt < 8; ++tt)
            acc += (tp[tt] * tp[tt]) *
                   *reinterpret_cast<const floatx4*>(wk + (8 + tt) * CC);

        floatx4 res;
#pragma unroll
        for (int o = 0; o < 4; ++o)
            res[o] = cxo[o] * __builtin_amdgcn_rsqf(acc[o]) * gov[o] + bov[o];

        __builtin_nontemporal_store(res,
            reinterpret_cast<floatx4*>(orow + w * CC + c0));
    }
}

extern "C" void kernel_launch(void* const* d_in, const int* in_sizes, int n_in,
                              void* d_out, int out_size, void* d_ws, size_t ws_size,
                              hipStream_t stream) {
    const float* x       = (const float*)d_in[0];
    const float* gamma_k = (const float*)d_in[1];
    const float* gamma_s = (const float*)d_in[2];
    const float* beta    = (const float*)d_in[3];
    const float* beta_o  = (const float*)d_in[4];
    const float* gamma_o = (const float*)d_in[5];
    const int*   sdist   = (const int*)d_in[6];
    float* out = (float*)d_out;

    const int blocks = BB * BLOCKS_PER_IMG;   // 6272
    dn_kernel<<<blocks, 256, 0, stream>>>(x, gamma_k, gamma_s, beta,
                                          beta_o, gamma_o, sdist, out);
}

// Round 5
// 225.354 us; speedup vs baseline: 2.2736x; 1.0063x over previous
//
#include <hip/hip_runtime.h>

typedef float floatx4 __attribute__((ext_vector_type(4)));

#define BB 32
#define HH 56
#define WW 56
#define CC 256
#define PSTRIP 4
#define WSTRIPS 14                      // 56/4
#define HTILE 4                         // rows per block (4 waves, 1 row each)
#define HTILES 14                       // 56/4
#define BLOCKS_PER_IMG (HTILES * WSTRIPS)  // 196

// R11: target VGPR <= 64 -- the HW occupancy cliff.
// R10 post-mortem: LDS-pin worked (budget 102, alloc 72, clean traffic,
// 93us best) but 72 VGPRs lands in the 65..128 HW bucket -> each wave
// holds a 128-reg slot -> 16 waves/CU -> 29% occupancy, 1.66 TB/s.
// Empirical law from R6-R10: occupancy follows the VGPR bucket
// (72->29%, 48->55%, 32->86%) and BW follows occupancy (1.66/3.4/4.0 TB/s).
// This round shrinks the live set to fit the <=64 bucket with NO spill:
//  - LDS = 20KB exactly -> 8 blocks/CU -> allocator target 8 waves/SIMD
//    -> budget exactly 64 (can't overshoot to 10 blocks and spill like
//    R7/R8, can't relax to 102 and alloc 72 like R10).
//  - betav/gov/bov move to LDS rows 16-18 (beta+1e-6 folded at staging;
//    3 ds_read_b128 per pixel to read back): -12 regs.
//  - taps processed in 2 batches of 4 through a reused tp[4]: 16 in-flight
//    tap regs instead of 32; WAR on tp lets the scheduler sink batch-B
//    loads under pressure instead of spilling.
// Live set ~= tp(16) + cxa/cxb(8) + cxo(4) + acc(4) + addressing(~12)
// + transients ~= 56 < 64.
// Clean 154MB at the 3.5-4 TB/s that 55-86% occupancy sustains => ~40us.
// Tripwires: VGPR_Count <= 64 (65-72 = neutral; FETCH/WRITE inflation =
// spill); LDS_Block_Size 20480.
__global__ __launch_bounds__(256) void dn_kernel(
    const float* __restrict__ x,
    const float* __restrict__ gk_g,
    const float* __restrict__ gs_g,
    const float* __restrict__ beta,
    const float* __restrict__ beta_o,
    const float* __restrict__ gamma_o,
    const int* __restrict__ sdist,
    float* __restrict__ out)
{
    // 20KB: rows 0-7 gk, 8-15 gsw, 16 beta+BETA_MIN, 17 gamma_o, 18 beta_o,
    // row 19 = occupancy-pinning pad (160/20 = exactly 8 blocks/CU).
    __shared__ float lw[20 * CC];

    const int tid = threadIdx.x;

    // Cooperative stage: 19 rows x 256 floats, dwordx4 per thread-iter.
    for (int idx = tid; idx < 19 * 64; idx += 256) {
        const int r  = idx >> 6;
        const int cq = (idx & 63) << 2;
        floatx4 v;
        if (r < 8) {
            v = *reinterpret_cast<const floatx4*>(gk_g + r * CC + cq);
        } else if (r < 16) {
            const int t   = r - 8;
            const int pos = t + (t >= 4 ? 1 : 0);   // skip center of 3x3
            v = *reinterpret_cast<const floatx4*>(gs_g + pos * CC + cq);
        } else if (r == 16) {
            v = *reinterpret_cast<const floatx4*>(beta + cq);
            v += 1e-6f;                             // fold BETA_MIN here
        } else if (r == 17) {
            v = *reinterpret_cast<const floatx4*>(gamma_o + cq);
        } else {
            v = *reinterpret_cast<const floatx4*>(beta_o + cq);
        }
        *reinterpret_cast<floatx4*>(&lw[r * CC + cq]) = v;
    }

    const int d    = sdist[0];                 // surround_dist (=1)
    const int xcd  = blockIdx.x & 7;
    const int q    = blockIdx.x >> 3;          // 0..783
    const int b    = xcd + ((q / BLOCKS_PER_IMG) << 3);
    const int t0   = q % BLOCKS_PER_IMG;
    const int h    = (t0 / WSTRIPS) * HTILE + (tid >> 6);
    const int w0   = (t0 % WSTRIPS) * PSTRIP;
    const int lane = tid & 63;
    const int c0   = lane << 2;                // own channel quad
    const int cg   = c0 & ~7;                  // group base (8 ch)

    const int tap_kh[8] = {0,0,0,1,1,2,2,2};
    const int tap_kw[8] = {0,1,2,0,2,0,1,2};

    const float* xb   = x + (size_t)b * HH * WW * CC;
    const float* xrow = xb + (size_t)h * WW * CC;
    float*       orow = out + ((size_t)(b * HH + h) * WW) * CC;
    const float* wk   = lw + c0;               // per-lane LDS base

    __syncthreads();

#pragma unroll
    for (int j = 0; j < PSTRIP; ++j) {
        const int w = w0 + j;
        const float* cp = xrow + w * CC;

        // center: full 8-ch group (lane pairs duplicate-read the same 32B)
        floatx4 cxa = *reinterpret_cast<const floatx4*>(cp + cg);
        floatx4 cxb = *reinterpret_cast<const floatx4*>(cp + cg + 4);

        // tap batch A (taps 0..3), wave-uniform predication
        floatx4 tp[4];
#pragma unroll
        for (int tt = 0; tt < 4; ++tt) {
            const int hh = h + (tap_kh[tt] - 1) * d;
            const int w2 = w + (tap_kw[tt] - 1) * d;
            floatx4 v = {0.f, 0.f, 0.f, 0.f};
            if ((unsigned)hh < HH && (unsigned)w2 < WW)
                v = *reinterpret_cast<const floatx4*>(
                        xb + (size_t)(hh * WW + w2) * CC + c0);
            tp[tt] = v;
        }

        // Pk under batch-A latency: 8 group inputs x own 4 outputs
        const floatx4 cxo = (lane & 1) ? cxb : cxa;
        const floatx4 sqa = cxa * cxa, sqb = cxb * cxb;
        floatx4 acc = *reinterpret_cast<const floatx4*>(wk + 16 * CC); // beta
#pragma unroll
        for (int i = 0; i < 4; ++i)
            acc += sqa[i] * *reinterpret_cast<const floatx4*>(wk + i * CC);
#pragma unroll
        for (int i = 0; i < 4; ++i)
            acc += sqb[i] * *reinterpret_cast<const floatx4*>(wk + (4 + i) * CC);

        // consume batch A
#pragma unroll
        for (int tt = 0; tt < 4; ++tt)
            acc += (tp[tt] * tp[tt]) *
                   *reinterpret_cast<const floatx4*>(wk + (8 + tt) * CC);

        // tap batch B (taps 4..7), reusing tp[]
#pragma unroll
        for (int tt = 4; tt < 8; ++tt) {
            const int hh = h + (tap_kh[tt] - 1) * d;
            const int w2 = w + (tap_kw[tt] - 1) * d;
            floatx4 v = {0.f, 0.f, 0.f, 0.f};
            if ((unsigned)hh < HH && (unsigned)w2 < WW)
                v = *reinterpret_cast<const floatx4*>(
                        xb + (size_t)(hh * WW + w2) * CC + c0);
            tp[tt - 4] = v;
        }
#pragma unroll
        for (int tt = 4; tt < 8; ++tt)
            acc += (tp[tt - 4] * tp[tt - 4]) *
                   *reinterpret_cast<const floatx4*>(wk + (8 + tt) * CC);

        // epilogue: gov/bov from LDS (transient regs)
        const floatx4 gov = *reinterpret_cast<const floatx4*>(wk + 17 * CC);
        const floatx4 bov = *reinterpret_cast<const floatx4*>(wk + 18 * CC);
        floatx4 res;
#pragma unroll
        for (int o = 0; o < 4; ++o)
            res[o] = cxo[o] * __builtin_amdgcn_rsqf(acc[o]) * gov[o] + bov[o];

        __builtin_nontemporal_store(res,
            reinterpret_cast<floatx4*>(orow + w * CC + c0));
    }
}

extern "C" void kernel_launch(void* const* d_in, const int* in_sizes, int n_in,
                              void* d_out, int out_size, void* d_ws, size_t ws_size,
                              hipStream_t stream) {
    const float* x       = (const float*)d_in[0];
    const float* gamma_k = (const float*)d_in[1];
    const float* gamma_s = (const float*)d_in[2];
    const float* beta    = (const float*)d_in[3];
    const float* beta_o  = (const float*)d_in[4];
    const float* gamma_o = (const float*)d_in[5];
    const int*   sdist   = (const int*)d_in[6];
    float* out = (float*)d_out;

    const int blocks = BB * BLOCKS_PER_IMG;   // 6272
    dn_kernel<<<blocks, 256, 0, stream>>>(x, gamma_k, gamma_s, beta,
                                          beta_o, gamma_o, sdist, out);
}